// Round 2
// baseline (89.075 us; speedup 1.0000x reference)
//
#include <hip/hip_runtime.h>
#include <hip/hip_bf16.h>

// FMICLLoss: out = -mean(s_pos) + ALPHA * ( sum_{i!=j} exp(-d2_ij/2) / (N(N-1)) + EPS )
// N=8192, D=256, SIGMA=1 (inv2s2=0.5), ALPHA=1.5, EPS=1e-8, NORM_EPS=1e-12.
//
// R15 (this round): R14 (81.59us measured, absmax 0.0) + finalize_kernel
// folded into pair_kernel via last-block threadfence reduction:
//  - done counter in ws, RE-ZEROED BY norm_kernel every launch (the prior
//    R4/R10 "atomic fusion" failures are consistent with a ws-resident
//    counter/accumulator being re-poisoned by the harness's 43.5us fill
//    between iterations — this removes that failure mode)
//  - negp_part stays a plain per-block store; last pair block re-reduces
//    spos_part + negp_part in double (numerics IDENTICAL to the old
//    finalize_kernel -> absmax should stay 0.0; no float atomics)
//  - writer: store -> __threadfence -> atomicAdd(cnt); reader (cnt==511):
//    __threadfence -> plain loads (canonical threadfence-reduction)
// Expected: -4..-6us (one dispatch boundary + finalize kernel).
//
// R14 ledger (unchanged): pair residual = MFMA floor (3.7us) + quarter-rate
// v_exp_f32 epilogue (~3us, structural: 67M exps) + static tail imbalance
// (~1.4us: 2080 = 512*4+32) + prologue/ramp. Harness-fixed: ~43.5us ws
// re-poison fill + ~3.5us restores + dispatch boundaries (coop launch
// failed R7).

#define N_ROWS 8192
#define DIM    256
#define LOG2E  1.4426950408889634f
#define GRID   512

typedef __attribute__((ext_vector_type(8))) int   int8v;
typedef __attribute__((ext_vector_type(4))) float f32x4;

#define GLDS16(gptr, lptr) \
  __builtin_amdgcn_global_load_lds((const __attribute__((address_space(1))) void*)(gptr), \
                                   (__attribute__((address_space(3))) void*)(lptr), 16, 0, 0)

// ---------------------------------------------------------------------------
// Kernel 1: row-normalize z1 -> fp8, s_pos via Gram trick (one reduce phase).
// Also re-zeroes the pair_kernel completion counter (ws is poisoned between
// iterations; stream order guarantees this lands before pair_kernel).
// ---------------------------------------------------------------------------
__global__ __launch_bounds__(256) void norm_kernel(
    const float* __restrict__ z1, const float* __restrict__ z2,
    unsigned char* __restrict__ z1n8, float* __restrict__ spos_part,
    unsigned int* __restrict__ done_cnt) {

    int tid  = threadIdx.x;
    int wave = tid >> 6, lane = tid & 63;
    int row  = blockIdx.x * 4 + wave;

    if (blockIdx.x == 0 && tid == 0) *done_cnt = 0u;

    const float4 a = *(const float4*)(z1 + (size_t)row * DIM + lane * 4);
    const float4 b = *(const float4*)(z2 + (size_t)row * DIM + lane * 4);

    float s1  = a.x*a.x + a.y*a.y + a.z*a.z + a.w*a.w;
    float s2  = b.x*b.x + b.y*b.y + b.z*b.z + b.w*b.w;
    float s12 = a.x*b.x + a.y*b.y + a.z*b.z + a.w*b.w;
    #pragma unroll
    for (int off = 32; off; off >>= 1) {       // 3 interleaved chains (ILP)
        s1  += __shfl_xor(s1,  off);
        s2  += __shfl_xor(s2,  off);
        s12 += __shfl_xor(s12, off);
    }
    float r1 = __builtin_amdgcn_rsqf(s1);
    float r2 = __builtin_amdgcn_rsqf(s2);

    int lo = __builtin_amdgcn_cvt_pk_fp8_f32(a.x * r1, a.y * r1, 0,  false);
    int pk = __builtin_amdgcn_cvt_pk_fp8_f32(a.z * r1, a.w * r1, lo, true);
    ((int*)(z1n8 + (size_t)row * DIM))[lane] = pk;

    __shared__ float sp[4];
    if (lane == 0) {
        float c = s12 * r1 * r2;               // d_pos = 2 - 2c
        sp[wave] = logf(__expf(c - 1.0f) + 1e-8f) + 1.0f;
    }
    __syncthreads();
    if (tid == 0)
        spos_part[blockIdx.x] = sp[0] + sp[1] + sp[2] + sp[3];
}

// ---------------------------------------------------------------------------
// Kernel 2: A-stationary fused fp8 Z·Z^T + exp-sum, upper block-triangle.
// Row-major strips: bids 0..31 -> 5 tiles, bids 32..511 -> 4 tiles.
// A-frags in VGPRs per strip; B staged per tile (K=128 dbuf, 1-chunk-ahead).
// Last block to finish performs the finalize reduction (double) and writes
// the output scalar — no separate finalize dispatch.
// ---------------------------------------------------------------------------
__global__ __launch_bounds__(256, 2) void pair_kernel(
    const unsigned char* __restrict__ z1n8, float* __restrict__ negp_part,
    const float* __restrict__ spos_part, unsigned int* __restrict__ done_cnt,
    float* __restrict__ out) {

    __shared__ unsigned char LA[2][128 * 128];   // A panel (2 K-chunks), 32 KB
    __shared__ unsigned char LB[2][128 * 128];   // B double buffer, 32 KB
    __shared__ float red[4];
    __shared__ int   last_flag;
    __shared__ double sd[4], nd[4];

    const int tid = threadIdx.x, wave = tid >> 6, lane = tid & 63;
    const int bid = blockIdx.x;
    const int wr = wave >> 1, wc = wave & 1;
    const int quad = lane >> 4, colL = lane & 15;
    const int c7 = colL & 7;
    const int rl = lane >> 3, cl = lane & 7;

    // strip [t0, t1): 5-tile strips on the earliest-dispatched 32 blocks
    int t0, t1;
    if (bid < 32) { t0 = 5 * bid;              t1 = t0 + 5; }
    else          { t0 = 160 + 4 * (bid - 32); t1 = t0 + 4; }

    int bi = (int)((129.0f - sqrtf(16641.0f - 8.0f * (float)t0)) * 0.5f);
    if (bi < 0) bi = 0;
    while (64 * bi - (bi - 1) * bi / 2 > t0) --bi;
    while (64 * (bi + 1) - bi * (bi + 1) / 2 <= t0) ++bi;
    int bj = bi + (t0 - (64 * bi - (bi - 1) * bi / 2));

    // stage one 128x128B panel-chunk: per issue 64 lanes x 16B = 8 rows;
    // stored 16B-block cl receives logical block cl ^ rl (XOR swizzle) so
    // ds_read_b128 is conflict-free with no padding.
    auto stageP = [&](const unsigned char* gP, unsigned char* dst, int kc) {
        const size_t so = (size_t)(wave * 32 + rl) * DIM + kc * 128 + ((cl ^ rl) << 4);
        unsigned char* d = dst + (wave * 32) * 128;
        #pragma unroll
        for (int q = 0; q < 4; ++q)
            GLDS16(gP + so + q * 8 * DIM, d + q * 1024);
    };
    auto stageA = [&](int pbi) {
        const unsigned char* g = z1n8 + (size_t)pbi * (128 * DIM);
        stageP(g, LA[0], 0);
        stageP(g, LA[1], 1);
    };
    auto stageB = [&](int buf, int pbj, int kc) {
        stageP(z1n8 + (size_t)pbj * (128 * DIM), LB[buf], kc);
    };

    int8v af[2][4];                              // A-frags: 64 VGPRs, strip-resident
    auto readA = [&]() {
        #pragma unroll
        for (int kc = 0; kc < 2; ++kc)
            #pragma unroll
            for (int m = 0; m < 4; ++m) {
                int base = (wr * 64 + m * 16 + colL) * 128;
                union { int8v v; uint4 q[2]; } u8;
                u8.q[0] = *(const uint4*)&LA[kc][base + (((quad * 2    ) ^ c7) << 4)];
                u8.q[1] = *(const uint4*)&LA[kc][base + (((quad * 2 + 1) ^ c7) << 4)];
                af[kc][m] = u8.v;
            }
    };

    auto computeB = [&](int buf, int kc, f32x4 (&accf)[4][4]) {
        int8v bf[4];
        #pragma unroll
        for (int n = 0; n < 4; ++n) {
            int base = (wc * 64 + n * 16 + colL) * 128;
            union { int8v v; uint4 q[2]; } u8;
            u8.q[0] = *(const uint4*)&LB[buf][base + (((quad * 2    ) ^ c7) << 4)];
            u8.q[1] = *(const uint4*)&LB[buf][base + (((quad * 2 + 1) ^ c7) << 4)];
            bf[n] = u8.v;
        }
        #pragma unroll
        for (int m = 0; m < 4; ++m)
            #pragma unroll
            for (int n = 0; n < 4; ++n)
                accf[m][n] = __builtin_amdgcn_mfma_scale_f32_16x16x128_f8f6f4(
                    af[kc][m], bf[n], accf[m][n],
                    0 /*fmtA=fp8*/, 0 /*fmtB=fp8*/,
                    0, 0x7F7F7F7F,   // scale A = 1.0 (E8M0 127)
                    0, 0x7F7F7F7F);  // scale B = 1.0
    };

    float tot[4] = {0.f, 0.f, 0.f, 0.f};         // 4 chains: break add latency

    // strip prologue: A (both chunks) + first B chunk, one drain, A -> VGPRs
    stageA(bi);
    stageB(0, bj, 0);
    __syncthreads();
    readA();

    for (int t = t0; t < t1; ++t) {
        stageB(1, bj, 1);                        // prefetch c1 (window: compute c0)

        f32x4 accf[4][4];
        #pragma unroll
        for (int m = 0; m < 4; ++m)
            #pragma unroll
            for (int n = 0; n < 4; ++n)
                accf[m][n] = f32x4{0.f, 0.f, 0.f, 0.f};

        computeB(0, 0, accf);
        __syncthreads();                         // publish LB[1], free LB[0]

        const int  nbj      = bj + 1;
        const bool more     = (t + 1 < t1);
        const bool crossing = (nbj >= 64);       // block-uniform
        if (more && !crossing)
            stageB(0, nbj, 0);                   // prefetch next tile c0
                                                 // (window: compute c1 + epilogue)
        computeB(1, 1, accf);

        // epilogue: ||u||^2==1 -> term = exp2(fma(dot, LOG2E, -LOG2E));
        // 4 independent accumulators (indexed by n) break the dep chain.
        if (bi != bj) {
            float l[4] = {0.f, 0.f, 0.f, 0.f};
            #pragma unroll
            for (int m = 0; m < 4; ++m)
                #pragma unroll
                for (int reg = 0; reg < 4; ++reg)
                    #pragma unroll
                    for (int n = 0; n < 4; ++n)
                        l[n] += __builtin_amdgcn_exp2f(
                            fmaf(accf[m][n][reg], LOG2E, -LOG2E));
            #pragma unroll
            for (int n = 0; n < 4; ++n)
                tot[n] += 2.0f * l[n];           // mirrored block
        } else {
            float l[4] = {0.f, 0.f, 0.f, 0.f};
            #pragma unroll
            for (int m = 0; m < 4; ++m)
                #pragma unroll
                for (int reg = 0; reg < 4; ++reg) {
                    int i = wr * 64 + m * 16 + quad * 4 + reg;
                    #pragma unroll
                    for (int n = 0; n < 4; ++n) {
                        int j = wc * 64 + n * 16 + colL;
                        float e = __builtin_amdgcn_exp2f(
                            fmaf(accf[m][n][reg], LOG2E, -LOG2E));
                        l[n] += (i == j) ? 0.0f : e;
                    }
                }
            #pragma unroll
            for (int n = 0; n < 4; ++n) tot[n] += l[n];
        }

        if (more) {
            if (crossing) {                      // new row: reload A, restart pipe
                ++bi; bj = bi;
                stageA(bi);
                stageB(0, bj, 0);
                __syncthreads();                 // drain A + B0 (LB[1] reads done)
                readA();
            } else {
                bj = nbj;
                __syncthreads();                 // publish LB[0], free LB[1]
            }
        }
    }

    // block-level reduction, once per kernel
    float total = (tot[0] + tot[1]) + (tot[2] + tot[3]);
    #pragma unroll
    for (int off = 32; off; off >>= 1) total += __shfl_down(total, off);
    if (lane == 0) red[wave] = total;
    __syncthreads();

    // publish partial, then last-block finalize (threadfence reduction)
    if (tid == 0) {
        negp_part[bid] = red[0] + red[1] + red[2] + red[3];
        __threadfence();                         // partial visible before count
        last_flag = (atomicAdd(done_cnt, 1u) == GRID - 1) ? 1 : 0;
    }
    __syncthreads();
    if (last_flag) {
        __threadfence();                         // acquire: see all partials
        double s = 0.0, ng = 0.0;
        for (int i = tid; i < 2048; i += 256) s  += (double)spos_part[i];
        for (int i = tid; i < GRID; i += 256) ng += (double)negp_part[i];
        #pragma unroll
        for (int off = 32; off; off >>= 1) {
            s  += __shfl_xor(s,  off);
            ng += __shfl_xor(ng, off);
        }
        if (lane == 0) { sd[wave] = s; nd[wave] = ng; }
        __syncthreads();
        if (tid == 0) {
            double st = sd[0] + sd[1] + sd[2] + sd[3];
            double nt = nd[0] + nd[1] + nd[2] + nd[3];
            double mean_star = nt / (8192.0 * 8191.0) + 1e-8;
            out[0] = (float)(-st / 8192.0 + 1.5 * mean_star);
        }
    }
}

extern "C" void kernel_launch(void* const* d_in, const int* in_sizes, int n_in,
                              void* d_out, int out_size, void* d_ws, size_t ws_size,
                              hipStream_t stream) {
    const float* z1 = (const float*)d_in[0];
    const float* z2 = (const float*)d_in[1];
    float* out = (float*)d_out;

    char* ws = (char*)d_ws;
    unsigned char* z1n8  = (unsigned char*)ws;                         // 2 MB fp8
    float* spos_part     = (float*)(ws + (size_t)N_ROWS * DIM);        // 8 KB
    float* negp_part     = spos_part + 2048;                           // 2 KB
    unsigned int* done_cnt = (unsigned int*)(negp_part + GRID);        // 4 B

    norm_kernel<<<N_ROWS / 4, 256, 0, stream>>>(z1, z2, z1n8, spos_part, done_cnt);
    pair_kernel<<<GRID, 256, 0, stream>>>(z1n8, negp_part, spos_part, done_cnt, out);
}

// Round 3
// 81.400 us; speedup vs baseline: 1.0943x; 1.0943x over previous
//
#include <hip/hip_runtime.h>
#include <hip/hip_bf16.h>

// FMICLLoss: out = -mean(s_pos) + ALPHA * ( sum_{i!=j} exp(-d2_ij/2) / (N(N-1)) + EPS )
// N=8192, D=256, SIGMA=1 (inv2s2=0.5), ALPHA=1.5, EPS=1e-8, NORM_EPS=1e-12.
//
// R16 = verbatim revert to R14 (best measured: 81.3us prior session /
// 81.59us R1 this session).
//
// R15 post-mortem (fused finalize into pair via last-block threadfence
// reduction): PASSED with absmax 0.0 (so the done-counter re-zeroed by
// norm_kernel correctly dodges the harness ws re-poison — correctness
// theory confirmed) but +7.5us total / ~+13us on pair itself. Attributed
// to a VGPR/spill cliff: pair at launch_bounds(256,2) is near the register
// budget (af 64 + accf 64 VGPRs); the double-precision finalize path forces
// spills that land in the hot K-loop. Fusion is now 3-for-3 measured-worse
// (R4/R10 poison-correctness, R7 coop, R15 spills) -> abandoned.
//
// Ledger: pair residual = MFMA floor (3.7us) + quarter-rate v_exp_f32
// epilogue (~3us, structural: 34M computed exps) + static tail imbalance
// (~2us: 2080 = 512*4+32, rebalance EV <1us) + prologue/ramp. Harness-fixed:
// ~43.5us ws re-poison fill + ~3.5us restores + ~12us dispatch boundaries.

#define N_ROWS 8192
#define DIM    256
#define LOG2E  1.4426950408889634f
#define GRID   512

typedef __attribute__((ext_vector_type(8))) int   int8v;
typedef __attribute__((ext_vector_type(4))) float f32x4;

#define GLDS16(gptr, lptr) \
  __builtin_amdgcn_global_load_lds((const __attribute__((address_space(1))) void*)(gptr), \
                                   (__attribute__((address_space(3))) void*)(lptr), 16, 0, 0)

// ---------------------------------------------------------------------------
// Kernel 1: row-normalize z1 -> fp8, s_pos via Gram trick (one reduce phase).
// ---------------------------------------------------------------------------
__global__ __launch_bounds__(256) void norm_kernel(
    const float* __restrict__ z1, const float* __restrict__ z2,
    unsigned char* __restrict__ z1n8, float* __restrict__ spos_part) {

    int tid  = threadIdx.x;
    int wave = tid >> 6, lane = tid & 63;
    int row  = blockIdx.x * 4 + wave;

    const float4 a = *(const float4*)(z1 + (size_t)row * DIM + lane * 4);
    const float4 b = *(const float4*)(z2 + (size_t)row * DIM + lane * 4);

    float s1  = a.x*a.x + a.y*a.y + a.z*a.z + a.w*a.w;
    float s2  = b.x*b.x + b.y*b.y + b.z*b.z + b.w*b.w;
    float s12 = a.x*b.x + a.y*b.y + a.z*b.z + a.w*b.w;
    #pragma unroll
    for (int off = 32; off; off >>= 1) {       // 3 interleaved chains (ILP)
        s1  += __shfl_xor(s1,  off);
        s2  += __shfl_xor(s2,  off);
        s12 += __shfl_xor(s12, off);
    }
    float r1 = __builtin_amdgcn_rsqf(s1);
    float r2 = __builtin_amdgcn_rsqf(s2);

    int lo = __builtin_amdgcn_cvt_pk_fp8_f32(a.x * r1, a.y * r1, 0,  false);
    int pk = __builtin_amdgcn_cvt_pk_fp8_f32(a.z * r1, a.w * r1, lo, true);
    ((int*)(z1n8 + (size_t)row * DIM))[lane] = pk;

    __shared__ float sp[4];
    if (lane == 0) {
        float c = s12 * r1 * r2;               // d_pos = 2 - 2c
        sp[wave] = logf(__expf(c - 1.0f) + 1e-8f) + 1.0f;
    }
    __syncthreads();
    if (tid == 0)
        spos_part[blockIdx.x] = sp[0] + sp[1] + sp[2] + sp[3];
}

// ---------------------------------------------------------------------------
// Kernel 2: A-stationary fused fp8 Z·Z^T + exp-sum, upper block-triangle.
// Row-major strips: bids 0..31 -> 5 tiles, bids 32..511 -> 4 tiles.
// A-frags in VGPRs per strip; B staged per tile (K=128 dbuf, 1-chunk-ahead).
// ---------------------------------------------------------------------------
__global__ __launch_bounds__(256, 2) void pair_kernel(
    const unsigned char* __restrict__ z1n8, float* __restrict__ negp_part) {

    __shared__ unsigned char LA[2][128 * 128];   // A panel (2 K-chunks), 32 KB
    __shared__ unsigned char LB[2][128 * 128];   // B double buffer, 32 KB
    __shared__ float red[4];

    const int tid = threadIdx.x, wave = tid >> 6, lane = tid & 63;
    const int bid = blockIdx.x;
    const int wr = wave >> 1, wc = wave & 1;
    const int quad = lane >> 4, colL = lane & 15;
    const int c7 = colL & 7;
    const int rl = lane >> 3, cl = lane & 7;

    // strip [t0, t1): 5-tile strips on the earliest-dispatched 32 blocks
    int t0, t1;
    if (bid < 32) { t0 = 5 * bid;              t1 = t0 + 5; }
    else          { t0 = 160 + 4 * (bid - 32); t1 = t0 + 4; }

    int bi = (int)((129.0f - sqrtf(16641.0f - 8.0f * (float)t0)) * 0.5f);
    if (bi < 0) bi = 0;
    while (64 * bi - (bi - 1) * bi / 2 > t0) --bi;
    while (64 * (bi + 1) - bi * (bi + 1) / 2 <= t0) ++bi;
    int bj = bi + (t0 - (64 * bi - (bi - 1) * bi / 2));

    // stage one 128x128B panel-chunk: per issue 64 lanes x 16B = 8 rows;
    // stored 16B-block cl receives logical block cl ^ rl (XOR swizzle) so
    // ds_read_b128 is conflict-free with no padding.
    auto stageP = [&](const unsigned char* gP, unsigned char* dst, int kc) {
        const size_t so = (size_t)(wave * 32 + rl) * DIM + kc * 128 + ((cl ^ rl) << 4);
        unsigned char* d = dst + (wave * 32) * 128;
        #pragma unroll
        for (int q = 0; q < 4; ++q)
            GLDS16(gP + so + q * 8 * DIM, d + q * 1024);
    };
    auto stageA = [&](int pbi) {
        const unsigned char* g = z1n8 + (size_t)pbi * (128 * DIM);
        stageP(g, LA[0], 0);
        stageP(g, LA[1], 1);
    };
    auto stageB = [&](int buf, int pbj, int kc) {
        stageP(z1n8 + (size_t)pbj * (128 * DIM), LB[buf], kc);
    };

    int8v af[2][4];                              // A-frags: 64 VGPRs, strip-resident
    auto readA = [&]() {
        #pragma unroll
        for (int kc = 0; kc < 2; ++kc)
            #pragma unroll
            for (int m = 0; m < 4; ++m) {
                int base = (wr * 64 + m * 16 + colL) * 128;
                union { int8v v; uint4 q[2]; } u8;
                u8.q[0] = *(const uint4*)&LA[kc][base + (((quad * 2    ) ^ c7) << 4)];
                u8.q[1] = *(const uint4*)&LA[kc][base + (((quad * 2 + 1) ^ c7) << 4)];
                af[kc][m] = u8.v;
            }
    };

    auto computeB = [&](int buf, int kc, f32x4 (&accf)[4][4]) {
        int8v bf[4];
        #pragma unroll
        for (int n = 0; n < 4; ++n) {
            int base = (wc * 64 + n * 16 + colL) * 128;
            union { int8v v; uint4 q[2]; } u8;
            u8.q[0] = *(const uint4*)&LB[buf][base + (((quad * 2    ) ^ c7) << 4)];
            u8.q[1] = *(const uint4*)&LB[buf][base + (((quad * 2 + 1) ^ c7) << 4)];
            bf[n] = u8.v;
        }
        #pragma unroll
        for (int m = 0; m < 4; ++m)
            #pragma unroll
            for (int n = 0; n < 4; ++n)
                accf[m][n] = __builtin_amdgcn_mfma_scale_f32_16x16x128_f8f6f4(
                    af[kc][m], bf[n], accf[m][n],
                    0 /*fmtA=fp8*/, 0 /*fmtB=fp8*/,
                    0, 0x7F7F7F7F,   // scale A = 1.0 (E8M0 127)
                    0, 0x7F7F7F7F);  // scale B = 1.0
    };

    float tot[4] = {0.f, 0.f, 0.f, 0.f};         // 4 chains: break add latency

    // strip prologue: A (both chunks) + first B chunk, one drain, A -> VGPRs
    stageA(bi);
    stageB(0, bj, 0);
    __syncthreads();
    readA();

    for (int t = t0; t < t1; ++t) {
        stageB(1, bj, 1);                        // prefetch c1 (window: compute c0)

        f32x4 accf[4][4];
        #pragma unroll
        for (int m = 0; m < 4; ++m)
            #pragma unroll
            for (int n = 0; n < 4; ++n)
                accf[m][n] = f32x4{0.f, 0.f, 0.f, 0.f};

        computeB(0, 0, accf);
        __syncthreads();                         // publish LB[1], free LB[0]

        const int  nbj      = bj + 1;
        const bool more     = (t + 1 < t1);
        const bool crossing = (nbj >= 64);       // block-uniform
        if (more && !crossing)
            stageB(0, nbj, 0);                   // prefetch next tile c0
                                                 // (window: compute c1 + epilogue)
        computeB(1, 1, accf);

        // epilogue: ||u||^2==1 -> term = exp2(fma(dot, LOG2E, -LOG2E));
        // 4 independent accumulators (indexed by n) break the dep chain.
        if (bi != bj) {
            float l[4] = {0.f, 0.f, 0.f, 0.f};
            #pragma unroll
            for (int m = 0; m < 4; ++m)
                #pragma unroll
                for (int reg = 0; reg < 4; ++reg)
                    #pragma unroll
                    for (int n = 0; n < 4; ++n)
                        l[n] += __builtin_amdgcn_exp2f(
                            fmaf(accf[m][n][reg], LOG2E, -LOG2E));
            #pragma unroll
            for (int n = 0; n < 4; ++n)
                tot[n] += 2.0f * l[n];           // mirrored block
        } else {
            float l[4] = {0.f, 0.f, 0.f, 0.f};
            #pragma unroll
            for (int m = 0; m < 4; ++m)
                #pragma unroll
                for (int reg = 0; reg < 4; ++reg) {
                    int i = wr * 64 + m * 16 + quad * 4 + reg;
                    #pragma unroll
                    for (int n = 0; n < 4; ++n) {
                        int j = wc * 64 + n * 16 + colL;
                        float e = __builtin_amdgcn_exp2f(
                            fmaf(accf[m][n][reg], LOG2E, -LOG2E));
                        l[n] += (i == j) ? 0.0f : e;
                    }
                }
            #pragma unroll
            for (int n = 0; n < 4; ++n) tot[n] += l[n];
        }

        if (more) {
            if (crossing) {                      // new row: reload A, restart pipe
                ++bi; bj = bi;
                stageA(bi);
                stageB(0, bj, 0);
                __syncthreads();                 // drain A + B0 (LB[1] reads done)
                readA();
            } else {
                bj = nbj;
                __syncthreads();                 // publish LB[0], free LB[1]
            }
        }
    }

    // block-level reduction, once per kernel
    float total = (tot[0] + tot[1]) + (tot[2] + tot[3]);
    #pragma unroll
    for (int off = 32; off; off >>= 1) total += __shfl_down(total, off);
    if (lane == 0) red[wave] = total;
    __syncthreads();
    if (tid == 0)
        negp_part[bid] = red[0] + red[1] + red[2] + red[3];
}

// ---------------------------------------------------------------------------
// Kernel 3: finalize — reduce partials in double, emit scalar.
// ---------------------------------------------------------------------------
__global__ __launch_bounds__(256) void finalize_kernel(
    const float* __restrict__ spos_part, const float* __restrict__ negp_part,
    float* __restrict__ out) {

    int tid = threadIdx.x;
    double s = 0.0, ng = 0.0;
    for (int i = tid; i < 2048; i += 256) s  += (double)spos_part[i];
    for (int i = tid; i < GRID; i += 256) ng += (double)negp_part[i];

    #pragma unroll
    for (int off = 32; off; off >>= 1) {
        s  += __shfl_xor(s,  off);
        ng += __shfl_xor(ng, off);
    }
    __shared__ double sd[4], nd[4];
    int wave = tid >> 6, lane = tid & 63;
    if (lane == 0) { sd[wave] = s; nd[wave] = ng; }
    __syncthreads();
    if (tid == 0) {
        double st = sd[0] + sd[1] + sd[2] + sd[3];
        double nt = nd[0] + nd[1] + nd[2] + nd[3];
        double mean_star = nt / (8192.0 * 8191.0) + 1e-8;
        out[0] = (float)(-st / 8192.0 + 1.5 * mean_star);
    }
}

extern "C" void kernel_launch(void* const* d_in, const int* in_sizes, int n_in,
                              void* d_out, int out_size, void* d_ws, size_t ws_size,
                              hipStream_t stream) {
    const float* z1 = (const float*)d_in[0];
    const float* z2 = (const float*)d_in[1];
    float* out = (float*)d_out;

    char* ws = (char*)d_ws;
    unsigned char* z1n8  = (unsigned char*)ws;                         // 2 MB fp8
    float* spos_part     = (float*)(ws + (size_t)N_ROWS * DIM);        // 8 KB
    float* negp_part     = spos_part + 2048;                           // 2 KB

    norm_kernel<<<N_ROWS / 4, 256, 0, stream>>>(z1, z2, z1n8, spos_part);
    pair_kernel<<<GRID, 256, 0, stream>>>(z1n8, negp_part);
    finalize_kernel<<<1, 256, 0, stream>>>(spos_part, negp_part, out);
}